// Round 1
// baseline (11990.617 us; speedup 1.0000x reference)
//
#include <hip/hip_runtime.h>
#include <math.h>

// Problem constants (match reference)
#define B_   4096
#define N_   50
#define D_   128
#define DV_  8
#define FS_  4
#define SE_  20
#define TPH_ 64
#define NEGV (-1e9f)
#define G_   16          // batch rows per decode block
#define NBLK (B_ / G_)   // 256 blocks

// ---------- fast math helpers (fp32, abs err ~1e-7 — safe for argmax) ----------
__device__ __forceinline__ float frcp_(float x) { return __builtin_amdgcn_rcpf(x); }
__device__ __forceinline__ float ftanh_(float x) {
    float e = __expf(2.f * x);               // inf-safe: x>>0 -> e=inf -> rcp=0 -> 1
    return 1.f - 2.f * frcp_(e + 1.f);
}
__device__ __forceinline__ float fsig_(float x) {
    return frcp_(1.f + __expf(-x));
}
__device__ __forceinline__ float wsum_(float v) {
#pragma unroll
    for (int m = 1; m < 64; m <<= 1) v += __shfl_xor(v, m);
    return v;
}

// ---------- kernel A: e = einsum('de,nbe->bnd', W, cu) + bias  -> [B][N][D] ----------
// block 256 = (d:128, rq:2); 20 rows staged in LDS per iter; W rows streamed from L2
// with 10-row register reuse per thread.
__global__ __launch_bounds__(256) void proj_kernel(
    const float* __restrict__ W,     // [128][128]
    const float* __restrict__ bias,  // [128]
    const float* __restrict__ cu,    // [N][B][D]
    float* __restrict__ outp)        // [B][N][D] (row r = b*N+n)
{
    __shared__ __align__(16) float scu[20][128];
    __shared__ float sb[128];
    const int tid = threadIdx.x;
    if (tid < 128) sb[tid] = bias[tid];
    const int d  = tid & 127;
    const int rq = tid >> 7;   // 0..1
    const float* wrow = W + d * 128;
    const int r0 = blockIdx.x * 200;
    for (int it = 0; it < 10; ++it) {
        const int rbase = r0 + it * 20;
        __syncthreads();   // protect scu from previous iteration's readers (covers sb too, iter 0)
        for (int i = tid; i < 20 * 128; i += 256) {
            int rr = i >> 7, e = i & 127;
            int r = rbase + rr;
            int b = r / 50, n = r - b * 50;
            scu[rr][e] = cu[((size_t)n * B_ + b) * D_ + e];
        }
        __syncthreads();
        float acc[10];
#pragma unroll
        for (int k = 0; k < 10; ++k) acc[k] = 0.f;
        const int rr0 = rq * 10;
        for (int e = 0; e < 128; e += 4) {
            float4 w4 = *(const float4*)&wrow[e];
#pragma unroll
            for (int k = 0; k < 10; ++k) {
                float4 c4 = *(const float4*)&scu[rr0 + k][e];   // wave-uniform: LDS broadcast
                acc[k] += w4.x * c4.x + w4.y * c4.y + w4.z * c4.z + w4.w * c4.w;
            }
        }
        float bv = sb[d];
#pragma unroll
        for (int k = 0; k < 10; ++k)
            outp[(size_t)(rbase + rr0 + k) * D_ + d] = acc[k] + bv;   // coalesced over d
    }
}

// ---------- kernel B: persistent 50-step decode, one block = 16 batch rows ----------
__global__ __launch_bounds__(1024) void decode_kernel(
    const float* __restrict__ dec_in,     // [B][D]
    const float* __restrict__ h0,
    const float* __restrict__ c0,
    const unsigned char* __restrict__ vmask,  // [B][N] bool bytes (all zero in this problem)
    const int* __restrict__ start_idx,    // [B]
    const float* __restrict__ V,          // [B][N][DV]
    const float* __restrict__ cu,         // [N][B][D]
    const float* __restrict__ start_fea,  // [B][FS]
    const float* __restrict__ W_ih,       // [512][128]
    const float* __restrict__ W_hh,       // [512][128]
    const float* __restrict__ b_ih, const float* __restrict__ b_hh,
    const float* __restrict__ gWq, const float* __restrict__ gbq,
    const float* __restrict__ gv,
    const float* __restrict__ pWq, const float* __restrict__ pbq,
    const float* __restrict__ pv,
    const float* __restrict__ step_table, // [51][20]
    const float* __restrict__ tpW1, const float* __restrict__ tpb1,  // [40][64],[64]
    const float* __restrict__ tpW2, const float* __restrict__ tpb2,  // [64],[1]
    const float* __restrict__ e_g, const float* __restrict__ e_p,    // [B][N][D]
    float* __restrict__ outp)
{
    __shared__ __align__(16) float sH[G_][D_];
    __shared__ __align__(16) float sC[G_][D_];
    __shared__ __align__(16) float sX[G_][D_];
    // sU: 16*512 floats. Gates live at sU[g*512+j]; after they are consumed,
    // qg/qp reuse sU[0:2048) (index g*128+d) and gl reuses sU[2048:4096).
    __shared__ __align__(16) float sU[G_ * 512];
    __shared__ float sBias[512];
    __shared__ __align__(16) float sGbq[128];
    __shared__ __align__(16) float sPbq[128];
    __shared__ __align__(16) float sGv[128];
    __shared__ __align__(16) float sPv[128];
    __shared__ float sSF[G_][FS_];
    __shared__ unsigned long long sMaskC[G_];
    __shared__ int sPrev[G_], sLast[G_];

    const int tid = threadIdx.x;
    const int b0  = blockIdx.x * G_;

    // ---- init ----
    for (int i = tid; i < G_ * D_; i += 1024) {
        int g = i >> 7, d = i & 127;
        size_t src = (size_t)(b0 + g) * D_ + d;
        sH[g][d] = h0[src];
        sC[g][d] = c0[src];
        sX[g][d] = dec_in[src];
    }
    if (tid < 512)       sBias[tid]      = b_ih[tid] + b_hh[tid];
    else if (tid < 640)  sGbq[tid - 512] = gbq[tid - 512];
    else if (tid < 768)  sPbq[tid - 640] = pbq[tid - 640];
    else if (tid < 896)  sGv[tid - 768]  = gv[tid - 768];
    else                 sPv[tid - 896]  = pv[tid - 896];
    if (tid < G_ * FS_) {
        int g = tid >> 2, k = tid & 3;
        sSF[g][k] = start_fea[(size_t)(b0 + g) * FS_ + k];
    }
    if (tid < G_) {
        unsigned long long mk = 0ull;
        const unsigned char* mrow = vmask + (size_t)(b0 + tid) * N_;
        for (int n = 0; n < N_; ++n)
            if (mrow[n]) mk |= (1ull << n);
        sMaskC[tid] = mk;
        sPrev[tid]  = 0;
        sLast[tid]  = start_idx[b0 + tid];
    }
    __syncthreads();

    const unsigned long long FULL = (1ull << N_) - 1ull;

    for (int t = 0; t < N_; ++t) {
        // ---- P0: mask update (16 threads; consumed 2+ barriers later) ----
        if (tid < G_) {
            unsigned long long mk = sMaskC[tid];
            if (t > 0) mk |= (1ull << sPrev[tid]);
            if ((mk & FULL) == FULL) mk &= ~(1ull << (N_ - 1));
            sMaskC[tid] = mk;
        }
        // ---- P1: gates = x@W_ih.T + h@W_hh.T + (b_ih+b_hh) ----
        {
            const int j  = tid & 511;
            const int gh = tid >> 9;      // 0/1 -> g halves
            const int gbase = gh * 8;
            const float* wih = W_ih + (size_t)j * 128;
            const float* whh = W_hh + (size_t)j * 128;
            float acc[8];
#pragma unroll
            for (int g = 0; g < 8; ++g) acc[g] = 0.f;
            for (int e = 0; e < 128; e += 16) {   // 64B/row per chunk: full L1 line use
                float4 wi[4], wh[4];
#pragma unroll
                for (int q = 0; q < 4; ++q) {
                    wi[q] = *(const float4*)&wih[e + 4 * q];
                    wh[q] = *(const float4*)&whh[e + 4 * q];
                }
#pragma unroll
                for (int g = 0; g < 8; ++g) {
                    const float* xr = &sX[gbase + g][e];
                    const float* hr = &sH[gbase + g][e];
#pragma unroll
                    for (int q = 0; q < 4; ++q) {
                        float4 x4 = *(const float4*)&xr[4 * q];  // wave-uniform broadcast
                        float4 h4 = *(const float4*)&hr[4 * q];
                        acc[g] += wi[q].x * x4.x + wi[q].y * x4.y + wi[q].z * x4.z + wi[q].w * x4.w
                                + wh[q].x * h4.x + wh[q].y * h4.y + wh[q].z * h4.z + wh[q].w * h4.w;
                    }
                }
            }
            float bb = sBias[j];
#pragma unroll
            for (int g = 0; g < 8; ++g) sU[(gbase + g) * 512 + j] = acc[g] + bb;
        }
        __syncthreads();

        // ---- P2: LSTM pointwise ----
        for (int i = tid; i < G_ * D_; i += 1024) {
            int g = i >> 7, d = i & 127;
            float ig = fsig_(sU[g * 512 + d]);
            float fg = fsig_(sU[g * 512 + 128 + d]);
            float gg = ftanh_(sU[g * 512 + 256 + d]);
            float og = fsig_(sU[g * 512 + 384 + d]);
            float c2 = fg * sC[g][d] + ig * gg;
            sC[g][d] = c2;
            sH[g][d] = og * ftanh_(c2);
        }
        __syncthreads();

        // ---- P3: qg = h2 @ gWq.T + gbq  -> sU[g*128+d] ----
        {
            const int d  = tid & 127;
            const int gh = tid >> 7;     // 0..7
            const int g0 = gh * 2;
            const float* wr = gWq + (size_t)d * 128;
            float a0 = 0.f, a1 = 0.f;
            for (int e = 0; e < 128; e += 16) {
                float4 w4[4];
#pragma unroll
                for (int q = 0; q < 4; ++q) w4[q] = *(const float4*)&wr[e + 4 * q];
#pragma unroll
                for (int q = 0; q < 4; ++q) {
                    float4 hA = *(const float4*)&sH[g0][e + 4 * q];
                    float4 hB = *(const float4*)&sH[g0 + 1][e + 4 * q];
                    a0 += w4[q].x * hA.x + w4[q].y * hA.y + w4[q].z * hA.z + w4[q].w * hA.w;
                    a1 += w4[q].x * hB.x + w4[q].y * hB.y + w4[q].z * hB.z + w4[q].w * hB.w;
                }
            }
            sU[g0 * 128 + d]       = a0 + sGbq[d];
            sU[(g0 + 1) * 128 + d] = a1 + sGbq[d];
        }
        __syncthreads();

        // ---- P4: glimpse, online-softmax, single pass over e_g tile; wave per g ----
        {
            const int g = tid >> 6;
            const int lane = tid & 63;
            const int b = b0 + g;
            const float qg1 = sU[g * 128 + lane];
            const float qg2 = sU[g * 128 + 64 + lane];
            const float gv1 = sGv[lane], gv2 = sGv[64 + lane];
            const unsigned long long mk = sMaskC[g];
            const float* egb = e_g + (size_t)b * (N_ * D_);
            float m = -__builtin_inff(), l = 0.f, a1 = 0.f, a2 = 0.f;
            float e1 = egb[lane], e2 = egb[64 + lane];   // n=0 prefetch
            for (int n = 0; n < N_; ++n) {
                float cur1 = e1, cur2 = e2;
                if (n + 1 < N_) {
                    e1 = egb[(n + 1) * 128 + lane];
                    e2 = egb[(n + 1) * 128 + 64 + lane];
                }
                float part = gv1 * ftanh_(qg1 + cur1) + gv2 * ftanh_(qg2 + cur2);
                float u = wsum_(part);
                if ((mk >> n) & 1ull) u = NEGV;
                float mn = fmaxf(m, u);
                float al = __expf(m - mn);   // m=-inf first iter -> 0
                float w  = __expf(u - mn);
                l  = l * al + w;
                a1 = a1 * al + w * cur1;
                a2 = a2 * al + w * cur2;
                m = mn;
            }
            float inv = 1.f / l;
            sU[2048 + g * 128 + lane]      = a1 * inv;
            sU[2048 + g * 128 + 64 + lane] = a2 * inv;
        }
        __syncthreads();

        // ---- P5: qp = gl @ pWq.T + pbq  -> sU[g*128+d] (qg region dead) ----
        {
            const int d  = tid & 127;
            const int gh = tid >> 7;
            const int g0 = gh * 2;
            const float* wr = pWq + (size_t)d * 128;
            float a0 = 0.f, a1 = 0.f;
            for (int e = 0; e < 128; e += 16) {
                float4 w4[4];
#pragma unroll
                for (int q = 0; q < 4; ++q) w4[q] = *(const float4*)&wr[e + 4 * q];
#pragma unroll
                for (int q = 0; q < 4; ++q) {
                    float4 hA = *(const float4*)&sU[2048 + g0 * 128 + e + 4 * q];
                    float4 hB = *(const float4*)&sU[2048 + (g0 + 1) * 128 + e + 4 * q];
                    a0 += w4[q].x * hA.x + w4[q].y * hA.y + w4[q].z * hA.z + w4[q].w * hA.w;
                    a1 += w4[q].x * hB.x + w4[q].y * hB.y + w4[q].z * hB.z + w4[q].w * hB.w;
                }
            }
            sU[g0 * 128 + d]       = a0 + sPbq[d];
            sU[(g0 + 1) * 128 + d] = a1 + sPbq[d];
        }
        __syncthreads();

        // ---- P6: pointer scores, log_softmax, argmax, MLP, next-x gather; wave per g ----
        {
            const int g = tid >> 6;
            const int lane = tid & 63;
            const int b = b0 + g;
            const bool active = lane < N_;
            const int n = active ? lane : (N_ - 1);   // clamp: valid reads, discarded
            const float* eprow = e_p + ((size_t)b * N_ + n) * D_;
            float up = 0.f;
            for (int e = 0; e < 128; e += 16) {
#pragma unroll
                for (int q = 0; q < 4; ++q) {
                    float4 p4 = *(const float4*)&eprow[e + 4 * q];
                    float4 q4 = *(const float4*)&sU[g * 128 + e + 4 * q];  // broadcast
                    float4 v4 = *(const float4*)&sPv[e + 4 * q];           // broadcast
                    up += v4.x * ftanh_(q4.x + p4.x) + v4.y * ftanh_(q4.y + p4.y)
                        + v4.z * ftanh_(q4.z + p4.z) + v4.w * ftanh_(q4.w + p4.w);
                }
            }
            const unsigned long long mk = sMaskC[g];
            float logit;
            if (!active)                logit = -__builtin_inff();
            else if ((mk >> n) & 1ull)  logit = NEGV;
            else                        logit = 10.0f * ftanh_(up);
            // log-softmax over lanes
            float mx = logit;
#pragma unroll
            for (int mm = 1; mm < 64; mm <<= 1) mx = fmaxf(mx, __shfl_xor(mx, mm));
            float ex = active ? __expf(logit - mx) : 0.f;
            float s = wsum_(ex);
            float lse = mx + __logf(s);
            if (active) outp[(size_t)b * (N_ * N_) + t * N_ + n] = logit - lse;
            // argmax, first-index tie-break (matches jnp.argmax)
            float av = logit; int ai = n;
#pragma unroll
            for (int mm = 1; mm < 64; mm <<= 1) {
                float ov = __shfl_xor(av, mm);
                int   oi = __shfl_xor(ai, mm);
                bool take = (ov > av) || (ov == av && oi < ai);
                av = take ? ov : av;
                ai = take ? oi : ai;
            }
            const int idx = ai;
            // time-prediction MLP: lane = hidden unit j (TPH_ == 64)
            const int lastv = sLast[g];
            const float* Vl = V + ((size_t)b * N_ + lastv) * DV_;
            const float* Vi = V + ((size_t)b * N_ + idx) * DV_;
            float hacc = tpb1[lane];
#pragma unroll
            for (int k = 0; k < 8; ++k)  hacc += Vl[k] * tpW1[k * 64 + lane];
#pragma unroll
            for (int k = 0; k < 8; ++k)  hacc += Vi[k] * tpW1[(8 + k) * 64 + lane];
#pragma unroll
            for (int k = 0; k < 4; ++k)  hacc += sSF[g][k] * tpW1[(16 + k) * 64 + lane];
#pragma unroll
            for (int k = 0; k < 20; ++k) hacc += step_table[t * SE_ + k] * tpW1[(20 + k) * 64 + lane];
            hacc = fmaxf(hacc, 0.f);
            float pred = wsum_(hacc * tpW2[lane]) + tpb2[0];
            // next decoder input x2 = context_update[idx, b]
            const float* xrow = cu + ((size_t)idx * B_ + b) * D_;
            float xa = xrow[lane], xb = xrow[64 + lane];
            sX[g][lane]      = xa;
            sX[g][64 + lane] = xb;
            if (lane == 0) {
                outp[(size_t)(B_ * N_) * N_ + (size_t)b * N_ + t]                          = (float)idx;
                outp[(size_t)(B_ * N_) * N_ + (size_t)(B_ * N_) + (size_t)b * N_ + t]      = pred;
                outp[(size_t)(B_ * N_) * N_ + 2 * (size_t)(B_ * N_) + (size_t)b * N_ + t]  = pred;
                sPrev[g] = idx;
                sLast[g] = idx;
            }
        }
        __syncthreads();
    }
}

extern "C" void kernel_launch(void* const* d_in, const int* in_sizes, int n_in,
                              void* d_out, int out_size, void* d_ws, size_t ws_size,
                              hipStream_t stream)
{
    const float* dec   = (const float*)d_in[0];
    const float* h0    = (const float*)d_in[1];
    const float* c0    = (const float*)d_in[2];
    const unsigned char* vmask = (const unsigned char*)d_in[3];
    const int*   sidx  = (const int*)d_in[4];
    const float* V     = (const float*)d_in[5];
    // d_in[6] b_E, d_in[7] b_E_abs, d_in[9] H_update: unused by reference
    const float* cu    = (const float*)d_in[8];
    const float* sfea  = (const float*)d_in[10];
    const float* W_ih  = (const float*)d_in[11];
    const float* W_hh  = (const float*)d_in[12];
    const float* b_ih  = (const float*)d_in[13];
    const float* b_hh  = (const float*)d_in[14];
    const float* gWq   = (const float*)d_in[15];
    const float* gbq   = (const float*)d_in[16];
    const float* gWr   = (const float*)d_in[17];
    const float* gbr   = (const float*)d_in[18];
    const float* gv    = (const float*)d_in[19];
    const float* pWq   = (const float*)d_in[20];
    const float* pbq   = (const float*)d_in[21];
    const float* pWr   = (const float*)d_in[22];
    const float* pbr   = (const float*)d_in[23];
    const float* pv    = (const float*)d_in[24];
    const float* stept = (const float*)d_in[25];
    const float* tpW1  = (const float*)d_in[26];
    const float* tpb1  = (const float*)d_in[27];
    const float* tpW2  = (const float*)d_in[28];
    const float* tpb2  = (const float*)d_in[29];

    float* e_g = (float*)d_ws;                       // [B][N][D] fp32
    float* e_p = e_g + (size_t)B_ * N_ * D_;         // needs 2*104.86 MB of ws

    // Precompute fixed attention keys (step-invariant)
    proj_kernel<<<dim3(1024), 256, 0, stream>>>(gWr, gbr, cu, e_g);
    proj_kernel<<<dim3(1024), 256, 0, stream>>>(pWr, pbr, cu, e_p);
    // Persistent 50-step decode: 256 blocks x 1024 threads, 16 batch rows/block
    decode_kernel<<<dim3(NBLK), 1024, 0, stream>>>(
        dec, h0, c0, vmask, sidx, V, cu, sfea,
        W_ih, W_hh, b_ih, b_hh,
        gWq, gbq, gv, pWq, pbq, pv,
        stept, tpW1, tpb1, tpW2, tpb2,
        e_g, e_p, (float*)d_out);
}